// Round 12
// baseline (113.168 us; speedup 1.0000x reference)
//
#include <hip/hip_runtime.h>
#include <hip/hip_bf16.h>
#include <stdint.h>
#include <stddef.h>

// ---------------------------------------------------------------------------
// InteractionPredictionHead: edge MLP.
// feats@W1 = P[src] + Q[dst] + attr@W1c + b1  (P,Q per-node, 50k not 300k).
// R12 (non-fused-path only; fused is BYTE-IDENTICAL to R11's 71.9us kernel):
//  - prep_pack: W1-only, remapped so OUT is fastest across threads ->
//    coalesced reads (was: j fastest -> 1KB-strided reads, one line per lane).
//  - W2/W3/W4/w1c packers moved into gemm1 grid as 84 tail blocks (images
//    consumed only by fused, which launches after gemm1 -> ordering safe).
// Layers 2-4: mfma_f32_16x16x32_bf16; gemm1: 32x32x16.
// ---------------------------------------------------------------------------

#define NN 50000
#define NE 300000
#define KG(kq,g2) ((kq)*2+(g2))
#define NBG1 391   // ceil(50000/128) gemm1 compute blocks

using bf16x8 = __attribute__((ext_vector_type(8))) short;
using f32x16 = __attribute__((ext_vector_type(16))) float;
using f32x4  = __attribute__((ext_vector_type(4))) float;
using f32x2  = __attribute__((ext_vector_type(2))) float;
using u32x4  = __attribute__((ext_vector_type(4))) unsigned int;
using u32x2  = __attribute__((ext_vector_type(2))) unsigned int;

// ---- ws layout (bytes, 16B aligned) ----
#define OFF_PQ   0ULL
#define SZ_PQ    (50000ULL*512ULL*2ULL)          // PQ bf16 [n][512]
#define OFF_W1   (OFF_PQ + SZ_PQ)                // W1 img (32-style) [kg32][512][8]
#define SZ_W1    (512ULL*256ULL*2ULL)
#define OFF_W1C  (OFF_W1 + SZ_W1)                // W1c f32 [3][256]
#define SZ_W1C   (3ULL*256ULL*4ULL)
#define OFF_W2   (OFF_W1C + SZ_W1C)              // W2 img (16-style) [sg32][128][8]
#define SZ_W2    (128ULL*256ULL*2ULL)
#define OFF_W3   (OFF_W2 + SZ_W2)                // W3 img (16-style) [sg16][64][8]
#define SZ_W3    (64ULL*128ULL*2ULL)
#define OFF_W4   (OFF_W3 + SZ_W3)                // W4 img (16-style) [sg8][16][8]
#define SZ_W4    (16ULL*64ULL*2ULL)
#define OFF_FLAG (OFF_W4 + SZ_W4)
#define WS_NEED  (OFF_FLAG + 16ULL)

__device__ __forceinline__ unsigned short f2bf(float x){
  unsigned u = __float_as_uint(x);
  unsigned r = 0x7FFFu + ((u >> 16) & 1u);
  return (unsigned short)((u + r) >> 16);
}
__device__ __forceinline__ unsigned cvtpk(float lo, float hi){
  unsigned r;
  asm("v_cvt_pk_bf16_f32 %0, %1, %2" : "=v"(r) : "v"(lo), "v"(hi));
  return r;
}
__device__ __forceinline__ f32x2 unpk(unsigned w){
  f32x2 r;
  r[0] = __uint_as_float(w << 16);
  r[1] = __uint_as_float(w & 0xFFFF0000u);
  return r;
}
__device__ __forceinline__ f32x16 mfma32(bf16x8 a, bf16x8 b, f32x16 c){
  return __builtin_amdgcn_mfma_f32_32x32x16_bf16(a, b, c, 0, 0, 0);
}
__device__ __forceinline__ f32x4 mfma16(bf16x8 a, bf16x8 b, f32x4 c){
  return __builtin_amdgcn_mfma_f32_16x16x32_bf16(a, b, c, 0, 0, 0);
}
__device__ __forceinline__ f32x16 zero16(){
  f32x16 v;
#pragma unroll
  for (int i = 0; i < 16; ++i) v[i] = 0.f;
  return v;
}

// ---------------------------------------------------------------------------
// prep_pack: W1 image only + int64 flag. OUT fastest -> coalesced reads.
// 131072 threads = 512 blocks x 256.
// ---------------------------------------------------------------------------
__global__ void prep_pack(const float* __restrict__ W1,
                          const int* __restrict__ ei32, char* __restrict__ ws)
{
  int i = blockIdx.x * 256 + threadIdx.x;
  unsigned short* w1i = (unsigned short*)(ws + OFF_W1);
  if (i < 131072){
    int out = i & 511;          // fastest across threads -> coalesced source
    int kgj = i >> 9;           // 0..255
    int kg = kgj >> 3, j = kgj & 7;
    int k = (kg >> 1)*16 + (kg & 1)*8 + j;
    float v = (out < 256) ? W1[(size_t)k*256 + out]
                          : W1[(size_t)(256 + k)*256 + (out - 256)];
    w1i[((size_t)kg*512 + out)*8 + j] = f2bf(v);
  }
  if (i == 0){
    int f = 1;
    for (int t = 1; t < 64; t += 2) if (ei32[t] != 0) { f = 0; break; }
    *(int*)(ws + OFF_FLAG) = f;
  }
}

// ---------------------------------------------------------------------------
// gemm1: blocks [0,NBG1): PQ = emb @ W1ab (+b1). 8 waves x 64 outs
// reg-stationary; 2 node-tiles of 64 per block.
// blocks [NBG1, NBG1+84): pack W2/W3/W4/w1c images (consumed only by fused).
// ---------------------------------------------------------------------------
__global__ __launch_bounds__(512, 2) void gemm1(const float* __restrict__ emb,
                                                const float* __restrict__ b1,
                                                const float* __restrict__ W1,
                                                const float* __restrict__ W2,
                                                const float* __restrict__ W3,
                                                const float* __restrict__ W4,
                                                char* __restrict__ ws)
{
  __shared__ __align__(16) unsigned short U[16896];   // 33792 B

  const int tid = threadIdx.x;
  const int bid = blockIdx.x;

  if (bid >= NBG1){
    // ---- packer blocks: W2 (32768) | W3 (8192) | W4 (1024) | w1c (768) ----
    int p = (bid - NBG1)*512 + tid;
    unsigned short* w2i = (unsigned short*)(ws + OFF_W2);
    unsigned short* w3i = (unsigned short*)(ws + OFF_W3);
    unsigned short* w4i = (unsigned short*)(ws + OFF_W4);
    float* w1c = (float*)(ws + OFF_W1C);
    if (p < 32768){
      int j = p & 7, out = (p >> 3) & 127, sg = p >> 10;
      int k = (sg >> 2)*32 + (sg & 3)*8 + j;
      w2i[p] = f2bf(W2[(size_t)k*128 + out]);
    } else if (p < 40960){
      int i3 = p - 32768;
      int j = i3 & 7, out = (i3 >> 3) & 63, sg = i3 >> 9;
      int k = (sg >> 2)*32 + (sg & 3)*8 + j;
      w3i[i3] = f2bf(W3[(size_t)k*64 + out]);
    } else if (p < 41984){
      int i4 = p - 40960;
      int j = i4 & 7, out = (i4 >> 3) & 15, sg = i4 >> 7;
      int k = (sg >> 2)*32 + (sg & 3)*8 + j;
      w4i[i4] = (out < 3) ? f2bf(W4[(size_t)k*3 + out]) : (unsigned short)0;
    } else if (p < 42752){
      int i5 = p - 41984;
      w1c[i5] = W1[(size_t)(512 + i5/256)*256 + (i5 & 255)];
    }
    return;
  }

  const int wv = tid >> 6, l = tid & 63, ln = l & 31, g2 = l >> 5;
  const int ob = wv * 64;
  const unsigned short* w1L = (const unsigned short*)(ws + OFF_W1);
  unsigned short* PQ = (unsigned short*)(ws + OFF_PQ);

  // reg-stationary weights: 2 tiles x 16 kq = 128 VGPR, loaded ONCE per block
  bf16x8 aw[2][16];
#pragma unroll
  for (int kq = 0; kq < 16; ++kq){
#pragma unroll
    for (int t2 = 0; t2 < 2; ++t2)
      aw[t2][kq] = *(const bf16x8*)(w1L + ((size_t)KG(kq,g2)*512 + ob + t2*32 + ln)*8);
  }

#pragma unroll 1
  for (int rep = 0; rep < 2; ++rep){
    const int nb = (bid*2 + rep) * 64;
    __syncthreads();   // previous rep's epilogue reads of U done

    // stage emb tile -> LDS bf16 k-major
#pragma unroll
    for (int it = 0; it < 8; ++it){
      int u = it*512 + tid;                      // 0..4095
      int kg = u >> 7, node = (u >> 1) & 63, half = u & 1;
      int n = nb + node; if (n >= NN) n = NN - 1;
      int k = (kg >> 1)*16 + (kg & 1)*8 + half*4;
      f32x4 e = *(const f32x4*)(emb + (size_t)n*256 + k);
      u32x2 w; w[0] = cvtpk(e[0], e[1]); w[1] = cvtpk(e[2], e[3]);
      *(u32x2*)(U + (size_t)kg*512 + node*8 + half*4) = w;
    }
    __syncthreads();

    f32x16 acc[2][2];
    acc[0][0] = zero16(); acc[0][1] = zero16();
    acc[1][0] = zero16(); acc[1][1] = zero16();
#pragma unroll
    for (int kq = 0; kq < 16; ++kq){
      bf16x8 b0  = *(const bf16x8*)(U + ((size_t)KG(kq,g2)*64 +      ln)*8);
      bf16x8 b1v = *(const bf16x8*)(U + ((size_t)KG(kq,g2)*64 + 32 + ln)*8);
      acc[0][0] = mfma32(aw[0][kq], b0,  acc[0][0]);
      acc[1][0] = mfma32(aw[1][kq], b0,  acc[1][0]);
      acc[0][1] = mfma32(aw[0][kq], b1v, acc[0][1]);
      acc[1][1] = mfma32(aw[1][kq], b1v, acc[1][1]);
    }
    __syncthreads();   // done reading emb staging; U becomes transpose buffer

    // epilogue: 2 passes of 32 nodes through padded LDS [32][516]
    const int r_ = tid >> 4;          // 0..31 (store row)
    const int j_ = tid & 15;          // 0..15 (store chunk)
#define G1PASS(BG)                                                             \
    {                                                                          \
      _Pragma("unroll")                                                        \
      for (int t2 = 0; t2 < 2; ++t2){                                          \
        _Pragma("unroll")                                                      \
        for (int rr = 0; rr < 4; ++rr){                                        \
          int o = ob + t2*32 + rr*8 + g2*4;                                    \
          f32x4 bv = {0.f,0.f,0.f,0.f};                                        \
          if (ob + t2*32 < 256) bv = *(const f32x4*)(b1 + o);                  \
          unsigned d0 = cvtpk(acc[t2][BG][rr*4+0]+bv[0], acc[t2][BG][rr*4+1]+bv[1]); \
          unsigned d1 = cvtpk(acc[t2][BG][rr*4+2]+bv[2], acc[t2][BG][rr*4+3]+bv[3]); \
          u32x2 st = {d0, d1};                                                 \
          *(u32x2*)(U + (size_t)ln*516 + o) = st;                              \
        }                                                                      \
      }                                                                        \
      __syncthreads();                                                         \
      {                                                                        \
        int n = nb + (BG)*32 + r_;                                             \
        if (n < NN){                                                           \
          _Pragma("unroll")                                                    \
          for (int ii = 0; ii < 4; ++ii){                                      \
            uint4 v = *(const uint4*)(U + (size_t)r_*516 + ii*128 + j_*8);     \
            *(uint4*)(PQ + (size_t)n*512 + ii*128 + j_*8) = v;                 \
          }                                                                    \
        }                                                                      \
      }                                                                        \
    }
    G1PASS(0);
    __syncthreads();
    G1PASS(1);
#undef G1PASS
  }
}

// ---------------------------------------------------------------------------
// fused: BYTE-IDENTICAL to R11 (71.9us). 512 thr (8 waves), 32 edges/wave,
// 16x16x32 MFMA. LDS: [0,64K) = W2 image -> (barrier) 8 x 8KB per-wave
// k-major h-slots; [64K,64K+3K) = w1c f32.  W3/W4 from L2.  2 barriers.
// ---------------------------------------------------------------------------

#define PAIRX(LO, HI, D) ((D)==0 ? (f32x2){(LO)[0],(LO)[1]} : \
                          (D)==1 ? (f32x2){(LO)[2],(LO)[3]} : \
                          (D)==2 ? (f32x2){(HI)[0],(HI)[1]} : \
                                   (f32x2){(HI)[2],(HI)[3]})

#define H1BUILD(PC, QC, A0, A1, A2, BOUT)                                      \
  {                                                                            \
    u32x4 pu = __builtin_bit_cast(u32x4, PC);                                  \
    u32x4 qu = __builtin_bit_cast(u32x4, QC);                                  \
    f32x2 z2 = {0.f, 0.f};                                                     \
    unsigned bu0, bu1, bu2, bu3;                                               \
    _Pragma("unroll")                                                          \
    for (int d = 0; d < 4; ++d){                                               \
      f32x2 h = unpk(pu[d]) + unpk(qu[d]);                                     \
      h += PAIRX(w0lo, w0hi, d) * (A0);                                        \
      h += PAIRX(w1lo, w1hi, d) * (A1);                                        \
      h += PAIRX(w2lo, w2hi, d) * (A2);                                        \
      h = __builtin_elementwise_max(h, z2);                                    \
      unsigned c = cvtpk(h[0], h[1]);                                          \
      if (d==0) bu0 = c; else if (d==1) bu1 = c; else if (d==2) bu2 = c;       \
      else bu3 = c;                                                            \
    }                                                                          \
    u32x4 buv = {bu0, bu1, bu2, bu3};                                          \
    BOUT = __builtin_bit_cast(bf16x8, buv);                                    \
  }

// one K=32 step: w1c slice, build 2 B-frags, reload bufs for S+2 (after use),
// then 8 A-frags x 2 groups = 16 MFMA.
#define L2S(S, P0, Q0, P1, Q1)                                                 \
  {                                                                            \
    const int kb = (S)*32 + g4*8;                                              \
    f32x4 w0lo = *(const f32x4*)(w1c_lds +   0 + kb);                          \
    f32x4 w0hi = *(const f32x4*)(w1c_lds +   4 + kb);                          \
    f32x4 w1lo = *(const f32x4*)(w1c_lds + 256 + kb);                          \
    f32x4 w1hi = *(const f32x4*)(w1c_lds + 260 + kb);                          \
    f32x4 w2lo = *(const f32x4*)(w1c_lds + 512 + kb);                          \
    f32x4 w2hi = *(const f32x4*)(w1c_lds + 516 + kb);                          \
    bf16x8 b0, b1;                                                             \
    H1BUILD(P0, Q0, at0e0, at1e0, at2e0, b0);                                  \
    H1BUILD(P1, Q1, at0e1, at1e1, at2e1, b1);                                  \
    if ((S) + 2 <= 7){                                                         \
      P0 = *(const bf16x8*)(Prow0 + ((S)+2)*32);                               \
      Q0 = *(const bf16x8*)(Qrow0 + ((S)+2)*32);                               \
      P1 = *(const bf16x8*)(Prow1 + ((S)+2)*32);                               \
      Q1 = *(const bf16x8*)(Qrow1 + ((S)+2)*32);                               \
    }                                                                          \
    const char* abase = smem + (size_t)((S)*4 + g4)*2048 + c16*16;             \
    _Pragma("unroll")                                                          \
    for (int t = 0; t < 8; ++t){                                               \
      bf16x8 af = *(const bf16x8*)(abase + t*256);                             \
      acc2[t][0] = mfma16(af, b0, acc2[t][0]);                                 \
      acc2[t][1] = mfma16(af, b1, acc2[t][1]);                                 \
    }                                                                          \
  }

__global__ __launch_bounds__(512, 4) void fused(const int* __restrict__ eidx,
                                                const float* __restrict__ attr,
                                                const float* __restrict__ b2,
                                                const float* __restrict__ b3,
                                                const float* __restrict__ b4,
                                                const char* __restrict__ ws,
                                                float* __restrict__ out)
{
  __shared__ __align__(16) char smem[65536 + 3072];
  const int tid = threadIdx.x;
  const int wv = tid >> 6, l = tid & 63, c16 = l & 15, g4 = l >> 4;

  const unsigned short* PQ  = (const unsigned short*)(ws + OFF_PQ);
  const unsigned short* w3g = (const unsigned short*)(ws + OFF_W3);
  const unsigned short* w4g = (const unsigned short*)(ws + OFF_W4);
  const float* W1c = (const float*)(ws + OFF_W1C);
  const int flag64 = *(const int*)(ws + OFF_FLAG);
  const float* w1c_lds = (const float*)(smem + 65536);

  const int ebase = blockIdx.x * 256 + wv * 32;
  const int e0 = ebase + c16,      e1 = ebase + 16 + c16;
  const bool ev0 = (e0 < NE),      ev1 = (e1 < NE);
  const int ec0 = ev0 ? e0 : 0,    ec1 = ev1 ? e1 : 0;
  const int si0 = flag64 ? eidx[2*(size_t)ec0]        : eidx[ec0];
  const int di0 = flag64 ? eidx[2*((size_t)NE + ec0)] : eidx[NE + ec0];
  const int si1 = flag64 ? eidx[2*(size_t)ec1]        : eidx[ec1];
  const int di1 = flag64 ? eidx[2*((size_t)NE + ec1)] : eidx[NE + ec1];

  const float at0e0 = ev0 ? attr[(size_t)ec0*3 + 0] : 0.f;
  const float at1e0 = ev0 ? attr[(size_t)ec0*3 + 1] : 0.f;
  const float at2e0 = ev0 ? attr[(size_t)ec0*3 + 2] : 0.f;
  const float at0e1 = ev1 ? attr[(size_t)ec1*3 + 0] : 0.f;
  const float at1e1 = ev1 ? attr[(size_t)ec1*3 + 1] : 0.f;
  const float at2e1 = ev1 ? attr[(size_t)ec1*3 + 2] : 0.f;

  const unsigned short* Prow0 = PQ + (size_t)si0*512 + g4*8;
  const unsigned short* Qrow0 = PQ + (size_t)di0*512 + 256 + g4*8;
  const unsigned short* Prow1 = PQ + (size_t)si1*512 + g4*8;
  const unsigned short* Qrow1 = PQ + (size_t)di1*512 + 256 + g4*8;

  // prime steps 0,1 (2-buffer rotation)
  bf16x8 pA0 = *(const bf16x8*)(Prow0 +  0), qA0 = *(const bf16x8*)(Qrow0 +  0);
  bf16x8 pA1 = *(const bf16x8*)(Prow1 +  0), qA1 = *(const bf16x8*)(Qrow1 +  0);
  bf16x8 pB0 = *(const bf16x8*)(Prow0 + 32), qB0 = *(const bf16x8*)(Qrow0 + 32);
  bf16x8 pB1 = *(const bf16x8*)(Prow1 + 32), qB1 = *(const bf16x8*)(Qrow1 + 32);

  // stage W2 (64KB) + w1c (3KB)
  {
    const uint4* src = (const uint4*)(ws + OFF_W2);
    uint4* dst = (uint4*)smem;
#pragma unroll
    for (int it = 0; it < 8; ++it) dst[it*512 + tid] = src[it*512 + tid];
    if (tid < 192) ((f32x4*)(smem + 65536))[tid] = ((const f32x4*)W1c)[tid];
  }
  __syncthreads();

  // ---------------- Layer 2: K=256 (8 steps), 128 outs, 32 edges -----------
  f32x4 acc2[8][2];
#pragma unroll
  for (int t = 0; t < 8; ++t){ acc2[t][0] = (f32x4){0,0,0,0}; acc2[t][1] = (f32x4){0,0,0,0}; }

  L2S(0, pA0, qA0, pA1, qA1);
  L2S(1, pB0, qB0, pB1, qB1);
  L2S(2, pA0, qA0, pA1, qA1);
  L2S(3, pB0, qB0, pB1, qB1);
  L2S(4, pA0, qA0, pA1, qA1);
  L2S(5, pB0, qB0, pB1, qB1);
  L2S(6, pA0, qA0, pA1, qA1);
  L2S(7, pB0, qB0, pB1, qB1);

  __syncthreads();   // all waves done reading W2 region

  // h2 -> per-wave k-major hslot [16 sg][32 edge][8] (8KB), +b2, bf16
  unsigned short* hslot = (unsigned short*)(smem + wv*8192);
#pragma unroll
  for (int t = 0; t < 8; ++t){
    f32x4 bv = *(const f32x4*)(b2 + t*16 + g4*4);
    const int sg_o = t*2 + (g4 >> 1);
    const int j0 = (g4 & 1)*4;
#pragma unroll
    for (int g = 0; g < 2; ++g){
      unsigned d0 = cvtpk(acc2[t][g][0]+bv[0], acc2[t][g][1]+bv[1]);
      unsigned d1 = cvtpk(acc2[t][g][2]+bv[2], acc2[t][g][3]+bv[3]);
      u32x2 st = {d0, d1};
      *(u32x2*)(hslot + ((sg_o*32 + g*16 + c16)*8 + j0)) = st;
    }
  }

  // ---------------- Layer 3: K=128 (4 steps), 64 outs; W3 from L2 ----------
  f32x4 acc3[4][2];
#pragma unroll
  for (int t = 0; t < 4; ++t){ acc3[t][0] = (f32x4){0,0,0,0}; acc3[t][1] = (f32x4){0,0,0,0}; }
#pragma unroll
  for (int ks = 0; ks < 4; ++ks){
    const int sg = ks*4 + g4;
    bf16x8 bb0 = *(const bf16x8*)(hslot + (sg*32 +      c16)*8);
    bf16x8 bb1 = *(const bf16x8*)(hslot + (sg*32 + 16 + c16)*8);
#pragma unroll
    for (int t = 0; t < 4; ++t){
      bf16x8 af = *(const bf16x8*)(w3g + ((size_t)sg*64 + t*16 + c16)*8);
      acc3[t][0] = mfma16(af, bb0, acc3[t][0]);
      acc3[t][1] = mfma16(af, bb1, acc3[t][1]);
    }
  }

  // h3 -> hslot base (relu, +b3); same-wave RAW on LDS is in-order
#pragma unroll
  for (int t = 0; t < 4; ++t){
    f32x4 bv = *(const f32x4*)(b3 + t*16 + g4*4);
    const int sg_o = t*2 + (g4 >> 1);
    const int j0 = (g4 & 1)*4;
#pragma unroll
    for (int g = 0; g < 2; ++g){
      unsigned d0 = cvtpk(fmaxf(acc3[t][g][0]+bv[0],0.f), fmaxf(acc3[t][g][1]+bv[1],0.f));
      unsigned d1 = cvtpk(fmaxf(acc3[t][g][2]+bv[2],0.f), fmaxf(acc3[t][g][3]+bv[3],0.f));
      u32x2 st = {d0, d1};
      *(u32x2*)(hslot + ((sg_o*32 + g*16 + c16)*8 + j0)) = st;
    }
  }

  // ---------------- Layer 4: K=64 (2 steps), 3 outs; W4 from L2 ------------
  f32x4 acc40 = {0,0,0,0}, acc41 = {0,0,0,0};
#pragma unroll
  for (int ks = 0; ks < 2; ++ks){
    const int sg = ks*4 + g4;
    bf16x8 af = *(const bf16x8*)(w4g + ((size_t)sg*16 + c16)*8);
    bf16x8 bb0 = *(const bf16x8*)(hslot + (sg*32 +      c16)*8);
    bf16x8 bb1 = *(const bf16x8*)(hslot + (sg*32 + 16 + c16)*8);
    acc40 = mfma16(af, bb0, acc40);
    acc41 = mfma16(af, bb1, acc41);
  }
  if (g4 == 0){
    float c0 = b4[0], c1 = b4[1], c2 = b4[2];
    if (ev0){
      out[(size_t)e0*3 + 0] = acc40[0] + c0;
      out[(size_t)e0*3 + 1] = acc40[1] + c1;
      out[(size_t)e0*3 + 2] = acc40[2] + c2;
    }
    if (ev1){
      out[(size_t)e1*3 + 0] = acc41[0] + c0;
      out[(size_t)e1*3 + 1] = acc41[1] + c1;
      out[(size_t)e1*3 + 2] = acc41[2] + c2;
    }
  }
}

// ---------------------------------------------------------------------------
extern "C" void kernel_launch(void* const* d_in, const int* in_sizes, int n_in,
                              void* d_out, int out_size, void* d_ws, size_t ws_size,
                              hipStream_t stream)
{
  const float* emb  = (const float*)d_in[0];
  const int*   eidx = (const int*)  d_in[1];
  const float* attr = (const float*)d_in[2];
  const float* W1   = (const float*)d_in[3];
  const float* b1   = (const float*)d_in[4];
  const float* W2   = (const float*)d_in[5];
  const float* b2   = (const float*)d_in[6];
  const float* W3   = (const float*)d_in[7];
  const float* b3   = (const float*)d_in[8];
  const float* W4   = (const float*)d_in[9];
  const float* b4   = (const float*)d_in[10];
  char* ws = (char*)d_ws;
  float* out = (float*)d_out;

  if (ws_size < WS_NEED) return;

  prep_pack<<<512, 256, 0, stream>>>(W1, eidx, ws);
  gemm1<<<NBG1 + 84, 512, 0, stream>>>(emb, b1, W1, W2, W3, W4, ws);
  fused<<<(NE + 255)/256, 512, 0, stream>>>(eidx, attr, b2, b3, b4, ws, out);
}

// Round 13
// 107.108 us; speedup vs baseline: 1.0566x; 1.0566x over previous
//
#include <hip/hip_runtime.h>
#include <hip/hip_bf16.h>
#include <stdint.h>
#include <stddef.h>

// ---------------------------------------------------------------------------
// InteractionPredictionHead: edge MLP.
// feats@W1 = P[src] + Q[dst] + attr@W1c + b1  (P,Q per-node, 50k not 300k).
// R13 (gemm1 only; fused BYTE-IDENTICAL to R11/R12's 71.9us kernel):
//  - gemm1: W1 fragments STREAMED from L2 inside K-loop (2-deep
//    reload-after-use) instead of 128-VGPR register-stationary preload ->
//    regs ~110 <= 128 -> launch_bounds(512,4) -> 2 blocks/CU -> the 6
//    barriers/tile overlap across blocks (was 1 block/CU, un-hidden stalls).
//    782 single-tile blocks (finer load balance; no rep loop since there is
//    no preload left to amortize).
//  - prep/packers: R12 verbatim (W1 coalesced prep; W2/W3/W4/w1c as gemm1
//    tail blocks).
// Layers 2-4: mfma_f32_16x16x32_bf16; gemm1: 32x32x16.
// ---------------------------------------------------------------------------

#define NN 50000
#define NE 300000
#define KG(kq,g2) ((kq)*2+(g2))
#define NBG1 782   // ceil(50000/64) gemm1 compute blocks

using bf16x8 = __attribute__((ext_vector_type(8))) short;
using f32x16 = __attribute__((ext_vector_type(16))) float;
using f32x4  = __attribute__((ext_vector_type(4))) float;
using f32x2  = __attribute__((ext_vector_type(2))) float;
using u32x4  = __attribute__((ext_vector_type(4))) unsigned int;
using u32x2  = __attribute__((ext_vector_type(2))) unsigned int;

// ---- ws layout (bytes, 16B aligned) ----
#define OFF_PQ   0ULL
#define SZ_PQ    (50000ULL*512ULL*2ULL)          // PQ bf16 [n][512]
#define OFF_W1   (OFF_PQ + SZ_PQ)                // W1 img (32-style) [kg32][512][8]
#define SZ_W1    (512ULL*256ULL*2ULL)
#define OFF_W1C  (OFF_W1 + SZ_W1)                // W1c f32 [3][256]
#define SZ_W1C   (3ULL*256ULL*4ULL)
#define OFF_W2   (OFF_W1C + SZ_W1C)              // W2 img (16-style) [sg32][128][8]
#define SZ_W2    (128ULL*256ULL*2ULL)
#define OFF_W3   (OFF_W2 + SZ_W2)                // W3 img (16-style) [sg16][64][8]
#define SZ_W3    (64ULL*128ULL*2ULL)
#define OFF_W4   (OFF_W3 + SZ_W3)                // W4 img (16-style) [sg8][16][8]
#define SZ_W4    (16ULL*64ULL*2ULL)
#define OFF_FLAG (OFF_W4 + SZ_W4)
#define WS_NEED  (OFF_FLAG + 16ULL)

__device__ __forceinline__ unsigned short f2bf(float x){
  unsigned u = __float_as_uint(x);
  unsigned r = 0x7FFFu + ((u >> 16) & 1u);
  return (unsigned short)((u + r) >> 16);
}
__device__ __forceinline__ unsigned cvtpk(float lo, float hi){
  unsigned r;
  asm("v_cvt_pk_bf16_f32 %0, %1, %2" : "=v"(r) : "v"(lo), "v"(hi));
  return r;
}
__device__ __forceinline__ f32x2 unpk(unsigned w){
  f32x2 r;
  r[0] = __uint_as_float(w << 16);
  r[1] = __uint_as_float(w & 0xFFFF0000u);
  return r;
}
__device__ __forceinline__ f32x16 mfma32(bf16x8 a, bf16x8 b, f32x16 c){
  return __builtin_amdgcn_mfma_f32_32x32x16_bf16(a, b, c, 0, 0, 0);
}
__device__ __forceinline__ f32x4 mfma16(bf16x8 a, bf16x8 b, f32x4 c){
  return __builtin_amdgcn_mfma_f32_16x16x32_bf16(a, b, c, 0, 0, 0);
}
__device__ __forceinline__ f32x16 zero16(){
  f32x16 v;
#pragma unroll
  for (int i = 0; i < 16; ++i) v[i] = 0.f;
  return v;
}

// ---------------------------------------------------------------------------
// prep_pack: W1 image only + int64 flag. OUT fastest -> coalesced reads.
// ---------------------------------------------------------------------------
__global__ void prep_pack(const float* __restrict__ W1,
                          const int* __restrict__ ei32, char* __restrict__ ws)
{
  int i = blockIdx.x * 256 + threadIdx.x;
  unsigned short* w1i = (unsigned short*)(ws + OFF_W1);
  if (i < 131072){
    int out = i & 511;
    int kgj = i >> 9;
    int kg = kgj >> 3, j = kgj & 7;
    int k = (kg >> 1)*16 + (kg & 1)*8 + j;
    float v = (out < 256) ? W1[(size_t)k*256 + out]
                          : W1[(size_t)(256 + k)*256 + (out - 256)];
    w1i[((size_t)kg*512 + out)*8 + j] = f2bf(v);
  }
  if (i == 0){
    int f = 1;
    for (int t = 1; t < 64; t += 2) if (ei32[t] != 0) { f = 0; break; }
    *(int*)(ws + OFF_FLAG) = f;
  }
}

// ---------------------------------------------------------------------------
// gemm1: blocks [0,NBG1): PQ = emb @ W1ab (+b1). 8 waves x 64 outs, W1 frags
// STREAMED from L2 (2-deep reload-after-use) -> ~110 regs -> 2 blocks/CU.
// blocks [NBG1, NBG1+84): pack W2/W3/W4/w1c images.
// ---------------------------------------------------------------------------
__global__ __launch_bounds__(512, 4) void gemm1(const float* __restrict__ emb,
                                                const float* __restrict__ b1,
                                                const float* __restrict__ W1,
                                                const float* __restrict__ W2,
                                                const float* __restrict__ W3,
                                                const float* __restrict__ W4,
                                                char* __restrict__ ws)
{
  __shared__ __align__(16) unsigned short U[16896];   // 33792 B

  const int tid = threadIdx.x;
  const int bid = blockIdx.x;

  if (bid >= NBG1){
    // ---- packer blocks: W2 (32768) | W3 (8192) | W4 (1024) | w1c (768) ----
    int p = (bid - NBG1)*512 + tid;
    unsigned short* w2i = (unsigned short*)(ws + OFF_W2);
    unsigned short* w3i = (unsigned short*)(ws + OFF_W3);
    unsigned short* w4i = (unsigned short*)(ws + OFF_W4);
    float* w1c = (float*)(ws + OFF_W1C);
    if (p < 32768){
      int j = p & 7, out = (p >> 3) & 127, sg = p >> 10;
      int k = (sg >> 2)*32 + (sg & 3)*8 + j;
      w2i[p] = f2bf(W2[(size_t)k*128 + out]);
    } else if (p < 40960){
      int i3 = p - 32768;
      int j = i3 & 7, out = (i3 >> 3) & 63, sg = i3 >> 9;
      int k = (sg >> 2)*32 + (sg & 3)*8 + j;
      w3i[i3] = f2bf(W3[(size_t)k*64 + out]);
    } else if (p < 41984){
      int i4 = p - 40960;
      int j = i4 & 7, out = (i4 >> 3) & 15, sg = i4 >> 7;
      int k = (sg >> 2)*32 + (sg & 3)*8 + j;
      w4i[i4] = (out < 3) ? f2bf(W4[(size_t)k*3 + out]) : (unsigned short)0;
    } else if (p < 42752){
      int i5 = p - 41984;
      w1c[i5] = W1[(size_t)(512 + i5/256)*256 + (i5 & 255)];
    }
    return;
  }

  const int wv = tid >> 6, l = tid & 63, ln = l & 31, g2 = l >> 5;
  const int ob = wv * 64;
  const int nb = bid * 64;
  const unsigned short* w1L = (const unsigned short*)(ws + OFF_W1);
  unsigned short* PQ = (unsigned short*)(ws + OFF_PQ);

  // stage emb tile -> LDS bf16 k-major
#pragma unroll
  for (int it = 0; it < 8; ++it){
    int u = it*512 + tid;                      // 0..4095
    int kg = u >> 7, node = (u >> 1) & 63, half = u & 1;
    int n = nb + node; if (n >= NN) n = NN - 1;
    int k = (kg >> 1)*16 + (kg & 1)*8 + half*4;
    f32x4 e = *(const f32x4*)(emb + (size_t)n*256 + k);
    u32x2 w; w[0] = cvtpk(e[0], e[1]); w[1] = cvtpk(e[2], e[3]);
    *(u32x2*)(U + (size_t)kg*512 + node*8 + half*4) = w;
  }

  // prime 2-deep W1-frag lookahead (L2-hot image) while staging flies
  bf16x8 awA0 = *(const bf16x8*)(w1L + ((size_t)KG(0,g2)*512 + ob +      ln)*8);
  bf16x8 awA1 = *(const bf16x8*)(w1L + ((size_t)KG(0,g2)*512 + ob + 32 + ln)*8);
  bf16x8 awB0 = *(const bf16x8*)(w1L + ((size_t)KG(1,g2)*512 + ob +      ln)*8);
  bf16x8 awB1 = *(const bf16x8*)(w1L + ((size_t)KG(1,g2)*512 + ob + 32 + ln)*8);

  __syncthreads();

  f32x16 acc[2][2];
  acc[0][0] = zero16(); acc[0][1] = zero16();
  acc[1][0] = zero16(); acc[1][1] = zero16();

  // K-loop: 16 kq, streamed weights (reload-after-use, distance 2)
#define G1STEP(KQ, W0, W1F)                                                    \
  {                                                                            \
    bf16x8 b0  = *(const bf16x8*)(U + ((size_t)KG(KQ,g2)*64 +      ln)*8);     \
    bf16x8 b1v = *(const bf16x8*)(U + ((size_t)KG(KQ,g2)*64 + 32 + ln)*8);     \
    bf16x8 a0 = W0, a1 = W1F;                                                  \
    if ((KQ) + 2 <= 15){                                                       \
      W0  = *(const bf16x8*)(w1L + ((size_t)KG((KQ)+2,g2)*512 + ob +      ln)*8); \
      W1F = *(const bf16x8*)(w1L + ((size_t)KG((KQ)+2,g2)*512 + ob + 32 + ln)*8); \
    }                                                                          \
    acc[0][0] = mfma32(a0, b0,  acc[0][0]);                                    \
    acc[1][0] = mfma32(a1, b0,  acc[1][0]);                                    \
    acc[0][1] = mfma32(a0, b1v, acc[0][1]);                                    \
    acc[1][1] = mfma32(a1, b1v, acc[1][1]);                                    \
  }
  G1STEP(0,  awA0, awA1);
  G1STEP(1,  awB0, awB1);
  G1STEP(2,  awA0, awA1);
  G1STEP(3,  awB0, awB1);
  G1STEP(4,  awA0, awA1);
  G1STEP(5,  awB0, awB1);
  G1STEP(6,  awA0, awA1);
  G1STEP(7,  awB0, awB1);
  G1STEP(8,  awA0, awA1);
  G1STEP(9,  awB0, awB1);
  G1STEP(10, awA0, awA1);
  G1STEP(11, awB0, awB1);
  G1STEP(12, awA0, awA1);
  G1STEP(13, awB0, awB1);
  G1STEP(14, awA0, awA1);
  G1STEP(15, awB0, awB1);
#undef G1STEP

  __syncthreads();   // done reading emb staging; U becomes transpose buffer

  // epilogue: 2 passes of 32 nodes through padded LDS [32][516]
  const int r_ = tid >> 4;          // 0..31 (store row)
  const int j_ = tid & 15;          // 0..15 (store chunk)
#define G1PASS(BG)                                                             \
  {                                                                            \
    _Pragma("unroll")                                                          \
    for (int t2 = 0; t2 < 2; ++t2){                                            \
      _Pragma("unroll")                                                        \
      for (int rr = 0; rr < 4; ++rr){                                          \
        int o = ob + t2*32 + rr*8 + g2*4;                                      \
        f32x4 bv = {0.f,0.f,0.f,0.f};                                          \
        if (ob + t2*32 < 256) bv = *(const f32x4*)(b1 + o);                    \
        unsigned d0 = cvtpk(acc[t2][BG][rr*4+0]+bv[0], acc[t2][BG][rr*4+1]+bv[1]); \
        unsigned d1 = cvtpk(acc[t2][BG][rr*4+2]+bv[2], acc[t2][BG][rr*4+3]+bv[3]); \
        u32x2 st = {d0, d1};                                                   \
        *(u32x2*)(U + (size_t)ln*516 + o) = st;                                \
      }                                                                        \
    }                                                                          \
    __syncthreads();                                                           \
    {                                                                          \
      int n = nb + (BG)*32 + r_;                                               \
      if (n < NN){                                                             \
        _Pragma("unroll")                                                      \
        for (int ii = 0; ii < 4; ++ii){                                        \
          uint4 v = *(const uint4*)(U + (size_t)r_*516 + ii*128 + j_*8);       \
          *(uint4*)(PQ + (size_t)n*512 + ii*128 + j_*8) = v;                   \
        }                                                                      \
      }                                                                        \
    }                                                                          \
  }
  G1PASS(0);
  __syncthreads();
  G1PASS(1);
#undef G1PASS
}

// ---------------------------------------------------------------------------
// fused: BYTE-IDENTICAL to R11/R12 (71.9us). 512 thr (8 waves), 32 edges/wave,
// 16x16x32 MFMA. LDS: [0,64K) = W2 image -> (barrier) 8 x 8KB per-wave
// k-major h-slots; [64K,64K+3K) = w1c f32.  W3/W4 from L2.  2 barriers.
// ---------------------------------------------------------------------------

#define PAIRX(LO, HI, D) ((D)==0 ? (f32x2){(LO)[0],(LO)[1]} : \
                          (D)==1 ? (f32x2){(LO)[2],(LO)[3]} : \
                          (D)==2 ? (f32x2){(HI)[0],(HI)[1]} : \
                                   (f32x2){(HI)[2],(HI)[3]})

#define H1BUILD(PC, QC, A0, A1, A2, BOUT)                                      \
  {                                                                            \
    u32x4 pu = __builtin_bit_cast(u32x4, PC);                                  \
    u32x4 qu = __builtin_bit_cast(u32x4, QC);                                  \
    f32x2 z2 = {0.f, 0.f};                                                     \
    unsigned bu0, bu1, bu2, bu3;                                               \
    _Pragma("unroll")                                                          \
    for (int d = 0; d < 4; ++d){                                               \
      f32x2 h = unpk(pu[d]) + unpk(qu[d]);                                     \
      h += PAIRX(w0lo, w0hi, d) * (A0);                                        \
      h += PAIRX(w1lo, w1hi, d) * (A1);                                        \
      h += PAIRX(w2lo, w2hi, d) * (A2);                                        \
      h = __builtin_elementwise_max(h, z2);                                    \
      unsigned c = cvtpk(h[0], h[1]);                                          \
      if (d==0) bu0 = c; else if (d==1) bu1 = c; else if (d==2) bu2 = c;       \
      else bu3 = c;                                                            \
    }                                                                          \
    u32x4 buv = {bu0, bu1, bu2, bu3};                                          \
    BOUT = __builtin_bit_cast(bf16x8, buv);                                    \
  }

#define L2S(S, P0, Q0, P1, Q1)                                                 \
  {                                                                            \
    const int kb = (S)*32 + g4*8;                                              \
    f32x4 w0lo = *(const f32x4*)(w1c_lds +   0 + kb);                          \
    f32x4 w0hi = *(const f32x4*)(w1c_lds +   4 + kb);                          \
    f32x4 w1lo = *(const f32x4*)(w1c_lds + 256 + kb);                          \
    f32x4 w1hi = *(const f32x4*)(w1c_lds + 260 + kb);                          \
    f32x4 w2lo = *(const f32x4*)(w1c_lds + 512 + kb);                          \
    f32x4 w2hi = *(const f32x4*)(w1c_lds + 516 + kb);                          \
    bf16x8 b0, b1;                                                             \
    H1BUILD(P0, Q0, at0e0, at1e0, at2e0, b0);                                  \
    H1BUILD(P1, Q1, at0e1, at1e1, at2e1, b1);                                  \
    if ((S) + 2 <= 7){                                                         \
      P0 = *(const bf16x8*)(Prow0 + ((S)+2)*32);                               \
      Q0 = *(const bf16x8*)(Qrow0 + ((S)+2)*32);                               \
      P1 = *(const bf16x8*)(Prow1 + ((S)+2)*32);                               \
      Q1 = *(const bf16x8*)(Qrow1 + ((S)+2)*32);                               \
    }                                                                          \
    const char* abase = smem + (size_t)((S)*4 + g4)*2048 + c16*16;             \
    _Pragma("unroll")                                                          \
    for (int t = 0; t < 8; ++t){                                               \
      bf16x8 af = *(const bf16x8*)(abase + t*256);                             \
      acc2[t][0] = mfma16(af, b0, acc2[t][0]);                                 \
      acc2[t][1] = mfma16(af, b1, acc2[t][1]);                                 \
    }                                                                          \
  }

__global__ __launch_bounds__(512, 4) void fused(const int* __restrict__ eidx,
                                                const float* __restrict__ attr,
                                                const float* __restrict__ b2,
                                                const float* __restrict__ b3,
                                                const float* __restrict__ b4,
                                                const char* __restrict__ ws,
                                                float* __restrict__ out)
{
  __shared__ __align__(16) char smem[65536 + 3072];
  const int tid = threadIdx.x;
  const int wv = tid >> 6, l = tid & 63, c16 = l & 15, g4 = l >> 4;

  const unsigned short* PQ  = (const unsigned short*)(ws + OFF_PQ);
  const unsigned short* w3g = (const unsigned short*)(ws + OFF_W3);
  const unsigned short* w4g = (const unsigned short*)(ws + OFF_W4);
  const float* W1c = (const float*)(ws + OFF_W1C);
  const int flag64 = *(const int*)(ws + OFF_FLAG);
  const float* w1c_lds = (const float*)(smem + 65536);

  const int ebase = blockIdx.x * 256 + wv * 32;
  const int e0 = ebase + c16,      e1 = ebase + 16 + c16;
  const bool ev0 = (e0 < NE),      ev1 = (e1 < NE);
  const int ec0 = ev0 ? e0 : 0,    ec1 = ev1 ? e1 : 0;
  const int si0 = flag64 ? eidx[2*(size_t)ec0]        : eidx[ec0];
  const int di0 = flag64 ? eidx[2*((size_t)NE + ec0)] : eidx[NE + ec0];
  const int si1 = flag64 ? eidx[2*(size_t)ec1]        : eidx[ec1];
  const int di1 = flag64 ? eidx[2*((size_t)NE + ec1)] : eidx[NE + ec1];

  const float at0e0 = ev0 ? attr[(size_t)ec0*3 + 0] : 0.f;
  const float at1e0 = ev0 ? attr[(size_t)ec0*3 + 1] : 0.f;
  const float at2e0 = ev0 ? attr[(size_t)ec0*3 + 2] : 0.f;
  const float at0e1 = ev1 ? attr[(size_t)ec1*3 + 0] : 0.f;
  const float at1e1 = ev1 ? attr[(size_t)ec1*3 + 1] : 0.f;
  const float at2e1 = ev1 ? attr[(size_t)ec1*3 + 2] : 0.f;

  const unsigned short* Prow0 = PQ + (size_t)si0*512 + g4*8;
  const unsigned short* Qrow0 = PQ + (size_t)di0*512 + 256 + g4*8;
  const unsigned short* Prow1 = PQ + (size_t)si1*512 + g4*8;
  const unsigned short* Qrow1 = PQ + (size_t)di1*512 + 256 + g4*8;

  // prime steps 0,1 (2-buffer rotation)
  bf16x8 pA0 = *(const bf16x8*)(Prow0 +  0), qA0 = *(const bf16x8*)(Qrow0 +  0);
  bf16x8 pA1 = *(const bf16x8*)(Prow1 +  0), qA1 = *(const bf16x8*)(Qrow1 +  0);
  bf16x8 pB0 = *(const bf16x8*)(Prow0 + 32), qB0 = *(const bf16x8*)(Qrow0 + 32);
  bf16x8 pB1 = *(const bf16x8*)(Prow1 + 32), qB1 = *(const bf16x8*)(Qrow1 + 32);

  // stage W2 (64KB) + w1c (3KB)
  {
    const uint4* src = (const uint4*)(ws + OFF_W2);
    uint4* dst = (uint4*)smem;
#pragma unroll
    for (int it = 0; it < 8; ++it) dst[it*512 + tid] = src[it*512 + tid];
    if (tid < 192) ((f32x4*)(smem + 65536))[tid] = ((const f32x4*)W1c)[tid];
  }
  __syncthreads();

  // ---------------- Layer 2: K=256 (8 steps), 128 outs, 32 edges -----------
  f32x4 acc2[8][2];
#pragma unroll
  for (int t = 0; t < 8; ++t){ acc2[t][0] = (f32x4){0,0,0,0}; acc2[t][1] = (f32x4){0,0,0,0}; }

  L2S(0, pA0, qA0, pA1, qA1);
  L2S(1, pB0, qB0, pB1, qB1);
  L2S(2, pA0, qA0, pA1, qA1);
  L2S(3, pB0, qB0, pB1, qB1);
  L2S(4, pA0, qA0, pA1, qA1);
  L2S(5, pB0, qB0, pB1, qB1);
  L2S(6, pA0, qA0, pA1, qA1);
  L2S(7, pB0, qB0, pB1, qB1);

  __syncthreads();   // all waves done reading W2 region

  // h2 -> per-wave k-major hslot [16 sg][32 edge][8] (8KB), +b2, bf16
  unsigned short* hslot = (unsigned short*)(smem + wv*8192);
#pragma unroll
  for (int t = 0; t < 8; ++t){
    f32x4 bv = *(const f32x4*)(b2 + t*16 + g4*4);
    const int sg_o = t*2 + (g4 >> 1);
    const int j0 = (g4 & 1)*4;
#pragma unroll
    for (int g = 0; g < 2; ++g){
      unsigned d0 = cvtpk(acc2[t][g][0]+bv[0], acc2[t][g][1]+bv[1]);
      unsigned d1 = cvtpk(acc2[t][g][2]+bv[2], acc2[t][g][3]+bv[3]);
      u32x2 st = {d0, d1};
      *(u32x2*)(hslot + ((sg_o*32 + g*16 + c16)*8 + j0)) = st;
    }
  }

  // ---------------- Layer 3: K=128 (4 steps), 64 outs; W3 from L2 ----------
  f32x4 acc3[4][2];
#pragma unroll
  for (int t = 0; t < 4; ++t){ acc3[t][0] = (f32x4){0,0,0,0}; acc3[t][1] = (f32x4){0,0,0,0}; }
#pragma unroll
  for (int ks = 0; ks < 4; ++ks){
    const int sg = ks*4 + g4;
    bf16x8 bb0 = *(const bf16x8*)(hslot + (sg*32 +      c16)*8);
    bf16x8 bb1 = *(const bf16x8*)(hslot + (sg*32 + 16 + c16)*8);
#pragma unroll
    for (int t = 0; t < 4; ++t){
      bf16x8 af = *(const bf16x8*)(w3g + ((size_t)sg*64 + t*16 + c16)*8);
      acc3[t][0] = mfma16(af, bb0, acc3[t][0]);
      acc3[t][1] = mfma16(af, bb1, acc3[t][1]);
    }
  }

  // h3 -> hslot base (relu, +b3); same-wave RAW on LDS is in-order
#pragma unroll
  for (int t = 0; t < 4; ++t){
    f32x4 bv = *(const f32x4*)(b3 + t*16 + g4*4);
    const int sg_o = t*2 + (g4 >> 1);
    const int j0 = (g4 & 1)*4;
#pragma unroll
    for (int g = 0; g < 2; ++g){
      unsigned d0 = cvtpk(fmaxf(acc3[t][g][0]+bv[0],0.f), fmaxf(acc3[t][g][1]+bv[1],0.f));
      unsigned d1 = cvtpk(fmaxf(acc3[t][g][2]+bv[2],0.f), fmaxf(acc3[t][g][3]+bv[3],0.f));
      u32x2 st = {d0, d1};
      *(u32x2*)(hslot + ((sg_o*32 + g*16 + c16)*8 + j0)) = st;
    }
  }

  // ---------------- Layer 4: K=64 (2 steps), 3 outs; W4 from L2 ------------
  f32x4 acc40 = {0,0,0,0}, acc41 = {0,0,0,0};
#pragma unroll
  for (int ks = 0; ks < 2; ++ks){
    const int sg = ks*4 + g4;
    bf16x8 af = *(const bf16x8*)(w4g + ((size_t)sg*16 + c16)*8);
    bf16x8 bb0 = *(const bf16x8*)(hslot + (sg*32 +      c16)*8);
    bf16x8 bb1 = *(const bf16x8*)(hslot + (sg*32 + 16 + c16)*8);
    acc40 = mfma16(af, bb0, acc40);
    acc41 = mfma16(af, bb1, acc41);
  }
  if (g4 == 0){
    float c0 = b4[0], c1 = b4[1], c2 = b4[2];
    if (ev0){
      out[(size_t)e0*3 + 0] = acc40[0] + c0;
      out[(size_t)e0*3 + 1] = acc40[1] + c1;
      out[(size_t)e0*3 + 2] = acc40[2] + c2;
    }
    if (ev1){
      out[(size_t)e1*3 + 0] = acc41[0] + c0;
      out[(size_t)e1*3 + 1] = acc41[1] + c1;
      out[(size_t)e1*3 + 2] = acc41[2] + c2;
    }
  }
}

// ---------------------------------------------------------------------------
extern "C" void kernel_launch(void* const* d_in, const int* in_sizes, int n_in,
                              void* d_out, int out_size, void* d_ws, size_t ws_size,
                              hipStream_t stream)
{
  const float* emb  = (const float*)d_in[0];
  const int*   eidx = (const int*)  d_in[1];
  const float* attr = (const float*)d_in[2];
  const float* W1   = (const float*)d_in[3];
  const float* b1   = (const float*)d_in[4];
  const float* W2   = (const float*)d_in[5];
  const float* b2   = (const float*)d_in[6];
  const float* W3   = (const float*)d_in[7];
  const float* b3   = (const float*)d_in[8];
  const float* W4   = (const float*)d_in[9];
  const float* b4   = (const float*)d_in[10];
  char* ws = (char*)d_ws;
  float* out = (float*)d_out;

  if (ws_size < WS_NEED) return;

  prep_pack<<<512, 256, 0, stream>>>(W1, eidx, ws);
  gemm1<<<NBG1 + 84, 512, 0, stream>>>(emb, b1, W1, W2, W3, W4, ws);
  fused<<<(NE + 255)/256, 512, 0, stream>>>(eidx, attr, b2, b3, b4, ws, out);
}